// Round 6
// baseline (37.488 us; speedup 1.0000x reference)
//
#include <hip/hip_runtime.h>
#include <math.h>

namespace {

constexpr int kNB    = 16;
constexpr int kFrame = 2048;
constexpr int kSub   = 8;    // packed stream length; lane owns 16 samples (2 streams of 8)

typedef float f32x2 __attribute__((ext_vector_type(2)));

__device__ inline f32x2 pk_fma(f32x2 a, f32x2 b, f32x2 c) {
    f32x2 d;
    asm("v_pk_fma_f32 %0, %1, %2, %3" : "=v"(d) : "v"(a), "v"(b), "v"(c));
    return d;
}
__device__ inline f32x2 pk_mul(f32x2 a, f32x2 b) {
    f32x2 d;
    asm("v_pk_mul_f32 %0, %1, %2" : "=v"(d) : "v"(a), "v"(b));
    return d;
}
__device__ inline f32x2 pk_add(f32x2 a, f32x2 b) {
    f32x2 d;
    asm("v_pk_add_f32 %0, %1, %2" : "=v"(d) : "v"(a), "v"(b));
    return d;
}

// Block: 256 threads = 4 waves = 2 channels; wave w: channel (w>>1), half (w&1).
// Each wave handles 1024 samples: lane owns 16 consecutive (2 packed streams of 8).
__global__ __launch_bounds__(256, 4)
void biquad_chain_kernel(const float* __restrict__ audio,
                         const float* __restrict__ params,
                         float* __restrict__ out)
{
    // per channel, per band: b0, b1, b2, -a1, -a2 (+pad)
    __shared__ float sC[2][kNB][8];
    // per channel, band, level L: A^(8*2^L) = al*A + be*I, L=0..6 (A^8..A^512)
    // [0]=al, [1]=be, [2]=ga=-a2*al, [3]=pad (16B-aligned levels)
    __shared__ float sLvl[2][kNB][7][4];
    // lo-wave half-frame deltas, double-buffered by band parity
    __shared__ float sD[2][2][2];

    const int tid  = threadIdx.x;
    const int w    = tid >> 6;
    const int lane = tid & 63;
    const int c    = w >> 1;          // channel within block
    const int h    = w & 1;           // half of frame
    const int ch   = blockIdx.x * 2 + c;
    const int bb   = ch >> 7;
    const int ff   = ch & 127;

    const float* pb = params + (size_t)bb * (50 * 128) + ff;

    // ---- coefficient preamble (lo waves only): lane i -> band i ----
    if (h == 0 && lane < kNB) {
        const int band = lane;
        const double fn = (double)pb[(band * 3 + 0) * 128];
        const double gn = (double)pb[(band * 3 + 1) * 128];
        const double qn = (double)pb[(band * 3 + 2) * 128];
        const double PI   = 3.14159265358979323846;
        const double LN10 = 2.302585092994046;

        const bool isHP = (band == 0), isLP = (band == kNB - 1);
        const bool isShelf = (band == 1) || (band == kNB - 2);
        const double flo = isHP ? 2.995732273553991
                        : isLP ? 8.517193191416238
                        : isShelf ? 3.912023005428146
                        : 4.605170185988092;
        const double fsp = isHP ? 3.2188758248682006
                        : isLP ? 1.3862943611198906
                        : isShelf ? 5.768320995793772
                        : 5.0106352940962555;

        // uniform transcendental block
        const double Q  = exp(-0.6931471805599453 + qn * 3.4657359027997265);
        const double fc = exp(flo + fn * fsp);
        const double w0 = (2.0 * PI / 96000.0) * fc;
        const double sw = sin(w0);
        const double cw = cos(w0);
        const double al = sw / (2.0 * Q);
        const double gdb = (isHP || isLP) ? 0.0 : (-24.0 + gn * 48.0);
        const double A   = exp(gdb * (LN10 / 40.0));
        const double sA  = sqrt(A);
        const double ge = isHP ? (-60.0 + (double)pb[48 * 128] * 60.0) * (LN10 / 20.0)
                        : isLP ? (-60.0 + (double)pb[49 * 128] * 60.0) * (LN10 / 20.0)
                        : 0.0;
        const double gm = exp(ge);

        double b0, b1, b2, a0, a1, a2;
        if (isHP) {
            b0 = (1.0 + cw) * 0.5; b1 = -(1.0 + cw); b2 = (1.0 + cw) * 0.5;
            a0 = 1.0 + al; a1 = -2.0 * cw; a2 = 1.0 - al;
        } else if (isLP) {
            b0 = (1.0 - cw) * 0.5; b1 = 1.0 - cw; b2 = (1.0 - cw) * 0.5;
            a0 = 1.0 + al; a1 = -2.0 * cw; a2 = 1.0 - al;
        } else if (band == 1) {                // low shelf
            const double s2 = 2.0 * sA * al;
            b0 = A * ((A + 1.0) - (A - 1.0) * cw + s2);
            b1 = 2.0 * A * ((A - 1.0) - (A + 1.0) * cw);
            b2 = A * ((A + 1.0) - (A - 1.0) * cw - s2);
            a0 = (A + 1.0) + (A - 1.0) * cw + s2;
            a1 = -2.0 * ((A - 1.0) + (A + 1.0) * cw);
            a2 = (A + 1.0) + (A - 1.0) * cw - s2;
        } else if (band == kNB - 2) {          // high shelf
            const double s2 = 2.0 * sA * al;
            b0 = A * ((A + 1.0) + (A - 1.0) * cw + s2);
            b1 = -2.0 * A * ((A - 1.0) + (A + 1.0) * cw);
            b2 = A * ((A + 1.0) + (A - 1.0) * cw - s2);
            a0 = (A + 1.0) - (A - 1.0) * cw + s2;
            a1 = 2.0 * ((A - 1.0) - (A + 1.0) * cw);
            a2 = (A + 1.0) - (A - 1.0) * cw - s2;
        } else {                               // peaking
            b0 = 1.0 + al * A; b1 = -2.0 * cw; b2 = 1.0 - al * A;
            a0 = 1.0 + al / A; a1 = -2.0 * cw; a2 = 1.0 - al / A;
        }
        const double inv  = 1.0 / a0;
        const double binv = inv * gm;
        b0 *= binv; b1 *= binv; b2 *= binv; a1 *= inv; a2 *= inv;

        sC[c][band][0] = (float)b0;
        sC[c][band][1] = (float)b1;
        sC[c][band][2] = (float)b2;
        sC[c][band][3] = (float)(-a1);
        sC[c][band][4] = (float)(-a2);

        // CH doubling: after iter s hold A^(2^(s+1)); store s=2..8 -> A^8..A^512
        double ap = 1.0, bp = 0.0;
        #pragma unroll
        for (int s = 0; s < 9; ++s) {
            const double an = ap * (2.0 * bp - a1 * ap);
            const double bn = bp * bp - a2 * (ap * ap);
            ap = an; bp = bn;
            if (s >= 2) {
                const int L = s - 2;
                sLvl[c][band][L][0] = (float)ap;
                sLvl[c][band][L][1] = (float)bp;
                sLvl[c][band][L][2] = (float)(-a2 * ap);
                sLvl[c][band][L][3] = 0.f;
            }
        }
    }
    __syncthreads();

    // ---- load 16 samples: streams (t, t+8), t=0..7 ----
    f32x2 X[kSub];
    {
        const float4* ap = reinterpret_cast<const float4*>(
            audio + (size_t)ch * kFrame + h * 1024 + lane * 16);
        #pragma unroll
        for (int k = 0; k < 2; ++k) {
            const float4 va = ap[k];
            const float4 vb = ap[k + 2];
            X[4 * k + 0] = f32x2{va.x, vb.x};
            X[4 * k + 1] = f32x2{va.y, vb.y};
            X[4 * k + 2] = f32x2{va.z, vb.z};
            X[4 * k + 3] = f32x2{va.w, vb.w};
        }
    }

    // ---- cascade ----
    for (int band = 0; band < kNB; ++band) {
        const float b0  = sC[c][band][0];
        const float b1  = sC[c][band][1];
        const float b2  = sC[c][band][2];
        const float na1 = sC[c][band][3];
        const float na2 = sC[c][band][4];
        const float* L  = &sLvl[c][band][0][0];
        const f32x2 b0p  = {b0, b0},  b1p = {b1, b1}, b2p = {b2, b2};
        const f32x2 na1p = {na1, na1}, na2p = {na2, na2};

        // phase 1: two independent zero-state 8-sample streams (packed)
        f32x2 s1 = {0.f, 0.f}, s2 = {0.f, 0.f};
        #pragma unroll
        for (int t = 0; t < kSub; ++t) {
            const f32x2 xv = X[t];
            const f32x2 y  = pk_fma(b0p, xv, s1);
            const f32x2 tm = pk_fma(b1p, xv, s2);
            s2 = pk_fma(na2p, y, pk_mul(b2p, xv));
            s1 = pk_fma(na1p, y, tm);
            X[t] = y;
        }

        // fold streams with A^8 (level 0): d = A^8*dA + dB
        const float al8 = L[0], be8 = L[1], ga8 = L[2];
        const float wf = fmaf(na1, s1.x, s2.x);
        const float d0 = fmaf(al8, wf, fmaf(be8, s1.x, s1.y));
        const float d1 = fmaf(ga8, s1.x, fmaf(be8, s2.x, s2.y));

        // exclusive affine scan across 64 lanes, M = A^16 (levels 1..6)
        float v0, v1;
        {
            const float e0 = __shfl_up(d0, 1);
            const float e1 = __shfl_up(d1, 1);
            v0 = (lane == 0) ? 0.f : e0;
            v1 = (lane == 0) ? 0.f : e1;
        }
        #pragma unroll
        for (int j = 0; j < 6; ++j) {
            const int s = 1 << j;
            const float alj = L[4 * (j + 1) + 0];
            const float bej = L[4 * (j + 1) + 1];
            const float gaj = L[4 * (j + 1) + 2];
            float t0 = __shfl_up(v0, (unsigned)s);
            float t1 = __shfl_up(v1, (unsigned)s);
            const bool ok = (lane >= s);
            t0 = ok ? t0 : 0.f;
            t1 = ok ? t1 : 0.f;
            const float wj = fmaf(na1, t0, t1);
            v0 = fmaf(alj, wj, fmaf(bej, t0, v0));
            v1 = fmaf(gaj, t0, fmaf(bej, t1, v1));
        }

        // lo wave publishes half-frame total D = A^16*E(63) + d(63)
        if (h == 0) {
            const float al16 = L[4], be16 = L[5], ga16 = L[6];
            const float wD = fmaf(na1, v0, v1);
            const float D0 = fmaf(al16, wD, fmaf(be16, v0, d0));
            const float D1 = fmaf(ga16, v0, fmaf(be16, v1, d1));
            if (lane == 63) {
                sD[c][band & 1][0] = D0;
                sD[c][band & 1][1] = D1;
            }
        }
        __syncthreads();

        // hi wave: incoming state += A^(16*lane) * D  (binary decomposition)
        if (h == 1) {
            float g0 = sD[c][band & 1][0];
            float g1 = sD[c][band & 1][1];
            #pragma unroll
            for (int j = 0; j < 6; ++j) {
                const float alj = L[4 * (j + 1) + 0];
                const float bej = L[4 * (j + 1) + 1];
                const float gaj = L[4 * (j + 1) + 2];
                const float wj = fmaf(na1, g0, g1);
                const float m0 = fmaf(alj, wj, bej * g0);
                const float m1 = fmaf(gaj, g0, bej * g1);
                const bool bit = ((lane >> j) & 1) != 0;
                g0 = bit ? m0 : g0;
                g1 = bit ? m1 : g1;
            }
            v0 += g0;
            v1 += g1;
        }

        // reconstruct stream-B incoming: uB = A^8*u + dA
        const float wr  = fmaf(na1, v0, v1);
        const float uB0 = fmaf(al8, wr, fmaf(be8, v0, s1.x));
        const float uB1 = fmaf(ga8, v0, fmaf(be8, v1, s2.x));

        // phase 2: packed homogeneous correction y(t) += [A^t * u]_0
        f32x2 w0 = {v0, uB0}, w1 = {v1, uB1};
        #pragma unroll
        for (int t = 0; t < kSub; ++t) {
            const f32x2 cc = w0;
            X[t] = pk_add(X[t], cc);
            w0 = pk_fma(na1p, cc, w1);
            w1 = pk_mul(na2p, cc);
        }
    }

    // ---- unpack + store ----
    {
        float4* op = reinterpret_cast<float4*>(
            out + (size_t)ch * kFrame + h * 1024 + lane * 16);
        #pragma unroll
        for (int k = 0; k < 2; ++k) {
            op[k]     = float4{X[4 * k + 0].x, X[4 * k + 1].x, X[4 * k + 2].x, X[4 * k + 3].x};
            op[k + 2] = float4{X[4 * k + 0].y, X[4 * k + 1].y, X[4 * k + 2].y, X[4 * k + 3].y};
        }
    }
}

} // namespace

extern "C" void kernel_launch(void* const* d_in, const int* in_sizes, int n_in,
                              void* d_out, int out_size, void* d_ws, size_t ws_size,
                              hipStream_t stream)
{
    (void)d_ws; (void)ws_size; (void)n_in; (void)in_sizes;
    const float* audio  = (const float*)d_in[0];
    const float* params = (const float*)d_in[1];
    float* outp = (float*)d_out;

    const int channels = out_size / kFrame;        // 2048
    const int blocks   = channels / 2;             // 2 channels per block

    hipLaunchKernelGGL(biquad_chain_kernel, dim3(blocks), dim3(256), 0, stream,
                       audio, params, outp);
}

// Round 7
// 34.615 us; speedup vs baseline: 1.0830x; 1.0830x over previous
//
#include <hip/hip_runtime.h>
#include <math.h>

namespace {

constexpr int kNB    = 16;
constexpr int kFrame = 2048;
constexpr int kSub   = 8;    // packed stream length; lane owns 16 samples (2 streams of 8)

typedef float f32x2 __attribute__((ext_vector_type(2)));

__device__ inline f32x2 pk_fma(f32x2 a, f32x2 b, f32x2 c) {
    f32x2 d;
    asm("v_pk_fma_f32 %0, %1, %2, %3" : "=v"(d) : "v"(a), "v"(b), "v"(c));
    return d;
}
__device__ inline f32x2 pk_mul(f32x2 a, f32x2 b) {
    f32x2 d;
    asm("v_pk_mul_f32 %0, %1, %2" : "=v"(d) : "v"(a), "v"(b));
    return d;
}
__device__ inline f32x2 pk_add(f32x2 a, f32x2 b) {
    f32x2 d;
    asm("v_pk_add_f32 %0, %1, %2" : "=v"(d) : "v"(a), "v"(b));
    return d;
}

// Block: 128 threads = 2 waves = 1 channel. Wave h processes half h of the frame
// (1024 samples; lane owns 16 consecutive = 2 packed streams of 8).
// Per band, lo wave hands its half-frame state delta to hi wave through LDS
// with a release/acquire flag (no block barrier in the band loop).
__global__ __launch_bounds__(128, 4)
void biquad_chain_kernel(const float* __restrict__ audio,
                         const float* __restrict__ params,
                         float* __restrict__ out)
{
    // per band, 8 float4s:
    // [0] = (b0, b1, b2, na1)
    // [1] = (na2, al8, be8, ga8)                      A^8
    // [2+j] = (al, be, ga, 0) for A^(16*2^j), j=0..5  A^16..A^512
    __shared__ float4 sK[kNB][8];
    __shared__ float  sD[kNB][2];
    __shared__ int    sFlag;

    const int tid  = threadIdx.x;
    const int h    = tid >> 6;        // half of frame
    const int lane = tid & 63;
    const int ch   = blockIdx.x;      // 0..2047
    const int bb   = ch >> 7;
    const int ff   = ch & 127;

    const float* pb = params + (size_t)bb * (50 * 128) + ff;

    if (tid == 0) sFlag = 0;

    // ---- coefficient preamble (lo wave): lane i -> band i ----
    if (h == 0 && lane < kNB) {
        const int band = lane;
        const double fn = (double)pb[(band * 3 + 0) * 128];
        const double gn = (double)pb[(band * 3 + 1) * 128];
        const double qn = (double)pb[(band * 3 + 2) * 128];
        const double PI   = 3.14159265358979323846;
        const double LN10 = 2.302585092994046;

        const bool isHP = (band == 0), isLP = (band == kNB - 1);
        const bool isShelf = (band == 1) || (band == kNB - 2);
        const double flo = isHP ? 2.995732273553991
                        : isLP ? 8.517193191416238
                        : isShelf ? 3.912023005428146
                        : 4.605170185988092;
        const double fsp = isHP ? 3.2188758248682006
                        : isLP ? 1.3862943611198906
                        : isShelf ? 5.768320995793772
                        : 5.0106352940962555;

        // uniform transcendental block
        const double Q  = exp(-0.6931471805599453 + qn * 3.4657359027997265);
        const double fc = exp(flo + fn * fsp);
        const double w0 = (2.0 * PI / 96000.0) * fc;
        const double sw = sin(w0);
        const double cw = cos(w0);
        const double al = sw / (2.0 * Q);
        const double gdb = (isHP || isLP) ? 0.0 : (-24.0 + gn * 48.0);
        const double A   = exp(gdb * (LN10 / 40.0));
        const double sA  = sqrt(A);
        const double ge = isHP ? (-60.0 + (double)pb[48 * 128] * 60.0) * (LN10 / 20.0)
                        : isLP ? (-60.0 + (double)pb[49 * 128] * 60.0) * (LN10 / 20.0)
                        : 0.0;
        const double gm = exp(ge);

        double b0, b1, b2, a0, a1, a2;
        if (isHP) {
            b0 = (1.0 + cw) * 0.5; b1 = -(1.0 + cw); b2 = (1.0 + cw) * 0.5;
            a0 = 1.0 + al; a1 = -2.0 * cw; a2 = 1.0 - al;
        } else if (isLP) {
            b0 = (1.0 - cw) * 0.5; b1 = 1.0 - cw; b2 = (1.0 - cw) * 0.5;
            a0 = 1.0 + al; a1 = -2.0 * cw; a2 = 1.0 - al;
        } else if (band == 1) {                // low shelf
            const double s2 = 2.0 * sA * al;
            b0 = A * ((A + 1.0) - (A - 1.0) * cw + s2);
            b1 = 2.0 * A * ((A - 1.0) - (A + 1.0) * cw);
            b2 = A * ((A + 1.0) - (A - 1.0) * cw - s2);
            a0 = (A + 1.0) + (A - 1.0) * cw + s2;
            a1 = -2.0 * ((A - 1.0) + (A + 1.0) * cw);
            a2 = (A + 1.0) + (A - 1.0) * cw - s2;
        } else if (band == kNB - 2) {          // high shelf
            const double s2 = 2.0 * sA * al;
            b0 = A * ((A + 1.0) + (A - 1.0) * cw + s2);
            b1 = -2.0 * A * ((A - 1.0) + (A + 1.0) * cw);
            b2 = A * ((A + 1.0) + (A - 1.0) * cw - s2);
            a0 = (A + 1.0) - (A - 1.0) * cw + s2;
            a1 = 2.0 * ((A - 1.0) - (A + 1.0) * cw);
            a2 = (A + 1.0) - (A - 1.0) * cw - s2;
        } else {                               // peaking
            b0 = 1.0 + al * A; b1 = -2.0 * cw; b2 = 1.0 - al * A;
            a0 = 1.0 + al / A; a1 = -2.0 * cw; a2 = 1.0 - al / A;
        }
        const double inv  = 1.0 / a0;
        const double binv = inv * gm;
        b0 *= binv; b1 *= binv; b2 *= binv; a1 *= inv; a2 *= inv;

        // CH doubling: after iter s hold A^(2^(s+1)); keep s=2 (A^8), s=3..8 (A^16..A^512)
        float lvl[7][3];
        double ap = 1.0, bp = 0.0;
        #pragma unroll
        for (int s = 0; s < 9; ++s) {
            const double an = ap * (2.0 * bp - a1 * ap);
            const double bn = bp * bp - a2 * (ap * ap);
            ap = an; bp = bn;
            if (s >= 2) {
                lvl[s - 2][0] = (float)ap;
                lvl[s - 2][1] = (float)bp;
                lvl[s - 2][2] = (float)(-a2 * ap);
            }
        }
        sK[band][0] = float4{(float)b0, (float)b1, (float)b2, (float)(-a1)};
        sK[band][1] = float4{(float)(-a2), lvl[0][0], lvl[0][1], lvl[0][2]};
        #pragma unroll
        for (int j = 0; j < 6; ++j)
            sK[band][2 + j] = float4{lvl[1 + j][0], lvl[1 + j][1], lvl[1 + j][2], 0.f};
    }
    __syncthreads();   // the only block barrier

    // ---- load 16 samples: streams (t, t+8), t=0..7 ----
    f32x2 X[kSub];
    {
        const float4* ap = reinterpret_cast<const float4*>(
            audio + (size_t)ch * kFrame + h * 1024 + lane * 16);
        #pragma unroll
        for (int k = 0; k < 2; ++k) {
            const float4 va = ap[k];
            const float4 vb = ap[k + 2];
            X[4 * k + 0] = f32x2{va.x, vb.x};
            X[4 * k + 1] = f32x2{va.y, vb.y};
            X[4 * k + 2] = f32x2{va.z, vb.z};
            X[4 * k + 3] = f32x2{va.w, vb.w};
        }
    }

    // ---- cascade ----
    for (int band = 0; band < kNB; ++band) {
        // batched const read: 8 float4 loads issued together
        const float4 k0 = sK[band][0];
        const float4 k1 = sK[band][1];
        const float4 L0 = sK[band][2];
        const float4 L1 = sK[band][3];
        const float4 L2 = sK[band][4];
        const float4 L3 = sK[band][5];
        const float4 L4 = sK[band][6];
        const float4 L5 = sK[band][7];
        const float b0 = k0.x, b1 = k0.y, b2 = k0.z, na1 = k0.w;
        const float na2 = k1.x, al8 = k1.y, be8 = k1.z, ga8 = k1.w;
        const f32x2 b0p  = {b0, b0},  b1p = {b1, b1}, b2p = {b2, b2};
        const f32x2 na1p = {na1, na1}, na2p = {na2, na2};

        // phase 1: two independent zero-state 8-sample streams (packed)
        f32x2 s1 = {0.f, 0.f}, s2 = {0.f, 0.f};
        #pragma unroll
        for (int t = 0; t < kSub; ++t) {
            const f32x2 xv = X[t];
            const f32x2 y  = pk_fma(b0p, xv, s1);
            const f32x2 tm = pk_fma(b1p, xv, s2);
            s2 = pk_fma(na2p, y, pk_mul(b2p, xv));
            s1 = pk_fma(na1p, y, tm);
            X[t] = y;
        }

        // fold streams with A^8: d = A^8*dA + dB
        const float wf = fmaf(na1, s1.x, s2.x);
        const float d0 = fmaf(al8, wf, fmaf(be8, s1.x, s1.y));
        const float d1 = fmaf(ga8, s1.x, fmaf(be8, s2.x, s2.y));

        // exclusive affine scan across 64 lanes, M = A^16 (L0..L5)
        float v0, v1;
        {
            const float e0 = __shfl_up(d0, 1);
            const float e1 = __shfl_up(d1, 1);
            v0 = (lane == 0) ? 0.f : e0;
            v1 = (lane == 0) ? 0.f : e1;
        }
        {
            const float4 Ls[6] = {L0, L1, L2, L3, L4, L5};
            #pragma unroll
            for (int j = 0; j < 6; ++j) {
                const int s = 1 << j;
                const float alj = Ls[j].x, bej = Ls[j].y, gaj = Ls[j].z;
                float t0 = __shfl_up(v0, (unsigned)s);
                float t1 = __shfl_up(v1, (unsigned)s);
                const bool ok = (lane >= s);
                t0 = ok ? t0 : 0.f;
                t1 = ok ? t1 : 0.f;
                const float wj = fmaf(na1, t0, t1);
                v0 = fmaf(alj, wj, fmaf(bej, t0, v0));
                v1 = fmaf(gaj, t0, fmaf(bej, t1, v1));
            }
        }

        if (h == 0) {
            // publish half-frame total D = A^16*E(63) + d(63); release flag
            const float wD = fmaf(na1, v0, v1);
            const float D0 = fmaf(L0.x, wD, fmaf(L0.y, v0, d0));
            const float D1 = fmaf(L0.z, v0, fmaf(L0.y, v1, d1));
            if (lane == 63) {
                sD[band][0] = D0;
                sD[band][1] = D1;
                __hip_atomic_store(&sFlag, band + 1, __ATOMIC_RELEASE,
                                   __HIP_MEMORY_SCOPE_WORKGROUP);
            }
        } else {
            // acquire-spin until lo wave published band's delta
            while (__hip_atomic_load(&sFlag, __ATOMIC_ACQUIRE,
                                     __HIP_MEMORY_SCOPE_WORKGROUP) < band + 1) {}
            float g0 = sD[band][0];
            float g1 = sD[band][1];
            // incoming state += A^(16*lane) * D (binary decomposition)
            const float4 Ls[6] = {L0, L1, L2, L3, L4, L5};
            #pragma unroll
            for (int j = 0; j < 6; ++j) {
                const float alj = Ls[j].x, bej = Ls[j].y, gaj = Ls[j].z;
                const float wj = fmaf(na1, g0, g1);
                const float m0 = fmaf(alj, wj, bej * g0);
                const float m1 = fmaf(gaj, g0, bej * g1);
                const bool bit = ((lane >> j) & 1) != 0;
                g0 = bit ? m0 : g0;
                g1 = bit ? m1 : g1;
            }
            v0 += g0;
            v1 += g1;
        }

        // reconstruct stream-B incoming: uB = A^8*u + dA
        const float wr  = fmaf(na1, v0, v1);
        const float uB0 = fmaf(al8, wr, fmaf(be8, v0, s1.x));
        const float uB1 = fmaf(ga8, v0, fmaf(be8, v1, s2.x));

        // phase 2: packed homogeneous correction y(t) += [A^t * u]_0
        f32x2 w0 = {v0, uB0}, w1 = {v1, uB1};
        #pragma unroll
        for (int t = 0; t < kSub; ++t) {
            const f32x2 cc = w0;
            X[t] = pk_add(X[t], cc);
            w0 = pk_fma(na1p, cc, w1);
            w1 = pk_mul(na2p, cc);
        }
    }

    // ---- unpack + store ----
    {
        float4* op = reinterpret_cast<float4*>(
            out + (size_t)ch * kFrame + h * 1024 + lane * 16);
        #pragma unroll
        for (int k = 0; k < 2; ++k) {
            op[k]     = float4{X[4 * k + 0].x, X[4 * k + 1].x, X[4 * k + 2].x, X[4 * k + 3].x};
            op[k + 2] = float4{X[4 * k + 0].y, X[4 * k + 1].y, X[4 * k + 2].y, X[4 * k + 3].y};
        }
    }
}

} // namespace

extern "C" void kernel_launch(void* const* d_in, const int* in_sizes, int n_in,
                              void* d_out, int out_size, void* d_ws, size_t ws_size,
                              hipStream_t stream)
{
    (void)d_ws; (void)ws_size; (void)n_in; (void)in_sizes;
    const float* audio  = (const float*)d_in[0];
    const float* params = (const float*)d_in[1];
    float* outp = (float*)d_out;

    const int channels = out_size / kFrame;        // 2048
    hipLaunchKernelGGL(biquad_chain_kernel, dim3(channels), dim3(128), 0, stream,
                       audio, params, outp);
}

// Round 8
// 26.485 us; speedup vs baseline: 1.4154x; 1.3070x over previous
//
#include <hip/hip_runtime.h>
#include <math.h>

namespace {

constexpr int kNB    = 16;
constexpr int kFrame = 2048;
constexpr int kHalf  = 16;   // packed stream length (2 streams of 16 = 32 samples/lane)

typedef float f32x2 __attribute__((ext_vector_type(2)));

__device__ inline f32x2 pk_fma(f32x2 a, f32x2 b, f32x2 c) {
    f32x2 d;
    asm("v_pk_fma_f32 %0, %1, %2, %3" : "=v"(d) : "v"(a), "v"(b), "v"(c));
    return d;
}
__device__ inline f32x2 pk_mul(f32x2 a, f32x2 b) {
    f32x2 d;
    asm("v_pk_mul_f32 %0, %1, %2" : "=v"(d) : "v"(a), "v"(b));
    return d;
}
__device__ inline f32x2 pk_add(f32x2 a, f32x2 b) {
    f32x2 d;
    asm("v_pk_add_f32 %0, %1, %2" : "=v"(d) : "v"(a), "v"(b));
    return d;
}

// DPP move: returns, per lane, the value selected by CTRL from another lane.
// bound_ctrl=1 -> out-of-range sources read 0.
template <int CTRL>
__device__ inline float dpp_f(float v) {
    return __int_as_float(
        __builtin_amdgcn_update_dpp(0, __float_as_int(v), CTRL, 0xF, 0xF, true));
}

// one uniform-matrix Kogge-Stone level via row_shr DPP (intra-row-16)
template <int CTRL>
__device__ inline void ks_level(float& v0, float& v1, const float4 M, const float na1) {
    const float t0 = dpp_f<CTRL>(v0);
    const float t1 = dpp_f<CTRL>(v1);
    const float w  = fmaf(na1, t0, t1);
    v0 = fmaf(M.x, w,  fmaf(M.y, t0, v0));
    v1 = fmaf(M.z, t0, fmaf(M.y, t1, v1));
}

// Block = 64 threads = 1 wave = 1 channel. Lane owns 32 consecutive samples
// (2 packed streams of 16). Scan across lanes is 100% DPP (no LDS round-trips).
__global__ __launch_bounds__(64)
void biquad_chain_kernel(const float* __restrict__ audio,
                         const float* __restrict__ params,
                         float* __restrict__ out)
{
    // sK[b][0] = (b0, b1, b2, na1); sK[b][1] = (na2, al16, be16, ga16)  [A^16]
    __shared__ float4 sK[kNB][2];
    // powT[b][i] = (al, be, ga, 0) for M^(i+1), M = A^32, i = 0..31 (pad col 33)
    __shared__ float4 powT[kNB][33];

    const int lane = threadIdx.x & 63;
    const int ch   = blockIdx.x;      // 0..2047
    const int bb   = ch >> 7;
    const int ff   = ch & 127;

    const float* pb = params + (size_t)bb * (50 * 128) + ff;

    // ---- preamble: all 64 lanes; lane -> (band = lane&15, part = lane>>4) ----
    {
        const int band = lane & 15;
        const int part = lane >> 4;
        const double fn = (double)pb[(band * 3 + 0) * 128];
        const double gn = (double)pb[(band * 3 + 1) * 128];
        const double qn = (double)pb[(band * 3 + 2) * 128];
        const double PI   = 3.14159265358979323846;
        const double LN10 = 2.302585092994046;

        const bool isHP = (band == 0), isLP = (band == kNB - 1);
        const bool isShelf = (band == 1) || (band == kNB - 2);
        const double flo = isHP ? 2.995732273553991
                        : isLP ? 8.517193191416238
                        : isShelf ? 3.912023005428146
                        : 4.605170185988092;
        const double fsp = isHP ? 3.2188758248682006
                        : isLP ? 1.3862943611198906
                        : isShelf ? 5.768320995793772
                        : 5.0106352940962555;

        // uniform transcendental block
        const double Q  = exp(-0.6931471805599453 + qn * 3.4657359027997265);
        const double fc = exp(flo + fn * fsp);
        const double w0 = (2.0 * PI / 96000.0) * fc;
        const double sw = sin(w0);
        const double cw = cos(w0);
        const double al = sw / (2.0 * Q);
        const double gdb = (isHP || isLP) ? 0.0 : (-24.0 + gn * 48.0);
        const double A   = exp(gdb * (LN10 / 40.0));
        const double sA  = sqrt(A);
        const double ge = isHP ? (-60.0 + (double)pb[48 * 128] * 60.0) * (LN10 / 20.0)
                        : isLP ? (-60.0 + (double)pb[49 * 128] * 60.0) * (LN10 / 20.0)
                        : 0.0;
        const double gm = exp(ge);

        double b0, b1, b2, a0, a1, a2;
        if (isHP) {
            b0 = (1.0 + cw) * 0.5; b1 = -(1.0 + cw); b2 = (1.0 + cw) * 0.5;
            a0 = 1.0 + al; a1 = -2.0 * cw; a2 = 1.0 - al;
        } else if (isLP) {
            b0 = (1.0 - cw) * 0.5; b1 = 1.0 - cw; b2 = (1.0 - cw) * 0.5;
            a0 = 1.0 + al; a1 = -2.0 * cw; a2 = 1.0 - al;
        } else if (band == 1) {                // low shelf
            const double s2 = 2.0 * sA * al;
            b0 = A * ((A + 1.0) - (A - 1.0) * cw + s2);
            b1 = 2.0 * A * ((A - 1.0) - (A + 1.0) * cw);
            b2 = A * ((A + 1.0) - (A - 1.0) * cw - s2);
            a0 = (A + 1.0) + (A - 1.0) * cw + s2;
            a1 = -2.0 * ((A - 1.0) + (A + 1.0) * cw);
            a2 = (A + 1.0) + (A - 1.0) * cw - s2;
        } else if (band == kNB - 2) {          // high shelf
            const double s2 = 2.0 * sA * al;
            b0 = A * ((A + 1.0) + (A - 1.0) * cw + s2);
            b1 = -2.0 * A * ((A - 1.0) + (A + 1.0) * cw);
            b2 = A * ((A + 1.0) + (A - 1.0) * cw - s2);
            a0 = (A + 1.0) - (A - 1.0) * cw + s2;
            a1 = 2.0 * ((A - 1.0) - (A + 1.0) * cw);
            a2 = (A + 1.0) - (A - 1.0) * cw - s2;
        } else {                               // peaking
            b0 = 1.0 + al * A; b1 = -2.0 * cw; b2 = 1.0 - al * A;
            a0 = 1.0 + al / A; a1 = -2.0 * cw; a2 = 1.0 - al / A;
        }
        const double inv  = 1.0 / a0;
        const double binv = inv * gm;
        b0 *= binv; b1 *= binv; b2 *= binv; a1 *= inv; a2 *= inv;

        // CH doubling chain for A^(2^k), k=1..9; keep A^16, A^32 (=M), A^256, A^512
        double alc = 1.0, bec = 0.0;
        double al16 = 0, be16 = 0, al32 = 0, be32 = 0;
        double al256 = 0, be256 = 0, al512 = 0, be512 = 0;
        #pragma unroll
        for (int k = 1; k <= 9; ++k) {
            const double a_ = alc, b_ = bec;
            alc = a_ * (2.0 * b_ - a1 * a_);
            bec = b_ * b_ - a2 * (a_ * a_);
            if (k == 4) { al16 = alc; be16 = bec; }
            if (k == 5) { al32 = alc; be32 = bec; }
            if (k == 8) { al256 = alc; be256 = bec; }
            if (k == 9) { al512 = alc; be512 = bec; }
        }
        // compose (x*y) in the A-algebra: (alx A + bex I)(aly A + bey I)
        auto cmp = [&](double alx, double bex, double aly, double bey,
                       double& alo, double& beo) {
            const double p = alx * aly;
            alo = alx * bey + bex * aly - a1 * p;
            beo = bex * bey - a2 * p;
        };

        // part start: S = M^(8*part+1)
        double Sa, Sb;
        if (part == 0)      { Sa = al32; Sb = be32; }
        else if (part == 1) { cmp(al256, be256, al32, be32, Sa, Sb); }
        else if (part == 2) { cmp(al512, be512, al32, be32, Sa, Sb); }
        else { double ta, tb; cmp(al512, be512, al256, be256, ta, tb);
               cmp(ta, tb, al32, be32, Sa, Sb); }

        #pragma unroll
        for (int j = 0; j < 8; ++j) {
            powT[band][8 * part + j] =
                float4{(float)Sa, (float)Sb, (float)(-a2 * Sa), 0.f};
            double na, nb;
            cmp(Sa, Sb, al32, be32, na, nb);
            Sa = na; Sb = nb;
        }
        if (part == 0) {
            sK[band][0] = float4{(float)b0, (float)b1, (float)b2, (float)(-a1)};
            sK[band][1] = float4{(float)(-a2), (float)al16, (float)be16,
                                 (float)(-a2 * al16)};
        }
    }
    __syncthreads();

    // ---- load 32 samples, pack as 2 streams of 16: X[t] = (x[t], x[t+16]) ----
    f32x2 X[kHalf];
    {
        const float4* ap = reinterpret_cast<const float4*>(
            audio + (size_t)ch * kFrame + lane * 32);
        #pragma unroll
        for (int k = 0; k < 4; ++k) {
            const float4 va = ap[k];
            const float4 vb = ap[k + 4];
            X[4 * k + 0] = f32x2{va.x, vb.x};
            X[4 * k + 1] = f32x2{va.y, vb.y};
            X[4 * k + 2] = f32x2{va.z, vb.z};
            X[4 * k + 3] = f32x2{va.w, vb.w};
        }
    }

    // ---- cascade ----
    for (int band = 0; band < kNB; ++band) {
        const float4 k0 = sK[band][0];
        const float4 k1 = sK[band][1];
        const float4 P1 = powT[band][0];
        const float4 P2 = powT[band][1];
        const float4 P4 = powT[band][3];
        const float4 P8 = powT[band][7];
        const float4 Pme = powT[band][lane & 15];   // M^((lane&15)+1)
        const float4 Qme = powT[band][lane & 31];   // M^((lane&31)+1)

        const float b0 = k0.x, b1 = k0.y, b2 = k0.z, na1 = k0.w;
        const float na2 = k1.x, al16 = k1.y, be16 = k1.z, ga16 = k1.w;
        const f32x2 b0p  = {b0, b0},  b1p = {b1, b1}, b2p = {b2, b2};
        const f32x2 na1p = {na1, na1}, na2p = {na2, na2};

        // phase 1: two independent zero-state 16-sample streams (packed)
        f32x2 s1 = {0.f, 0.f}, s2 = {0.f, 0.f};
        #pragma unroll
        for (int t = 0; t < kHalf; ++t) {
            const f32x2 xv = X[t];
            const f32x2 y  = pk_fma(b0p, xv, s1);
            const f32x2 tm = pk_fma(b1p, xv, s2);
            s2 = pk_fma(na2p, y, pk_mul(b2p, xv));
            s1 = pk_fma(na1p, y, tm);
            X[t] = y;
        }

        // fold streams with A^16: d = A^16*dA + dB
        const float wf = fmaf(na1, s1.x, s2.x);
        const float d0 = fmaf(al16, wf, fmaf(be16, s1.x, s1.y));
        const float d1 = fmaf(ga16, s1.x, fmaf(be16, s2.x, s2.y));

        // ---- DS-free exclusive affine scan over 64 chunks, M = A^32 ----
        // exclusive shift by 1 (lane 0 -> 0) via wave_shr:1
        float v0 = dpp_f<0x138>(d0);
        float v1 = dpp_f<0x138>(d1);
        // intra-row-16 Kogge-Stone, distances 1,2,4,8 (row_shr, zero-fill)
        ks_level<0x111>(v0, v1, P1, na1);
        ks_level<0x112>(v0, v1, P2, na1);
        ks_level<0x114>(v0, v1, P4, na1);
        ks_level<0x118>(v0, v1, P8, na1);
        // row_bcast15: rows 1,3 receive prev row's lane-15 prefix; per-lane power
        {
            float t0 = dpp_f<0x142>(v0);
            float t1 = dpp_f<0x142>(v1);
            const bool g = (lane & 16) != 0;
            t0 = g ? t0 : 0.f;
            t1 = g ? t1 : 0.f;
            const float w = fmaf(na1, t0, t1);
            v0 = fmaf(Pme.x, w,  fmaf(Pme.y, t0, v0));
            v1 = fmaf(Pme.z, t0, fmaf(Pme.y, t1, v1));
        }
        // row_bcast31: lanes 32-63 receive lane-31 prefix; per-lane power
        {
            float t0 = dpp_f<0x143>(v0);
            float t1 = dpp_f<0x143>(v1);
            const bool g = lane >= 32;
            t0 = g ? t0 : 0.f;
            t1 = g ? t1 : 0.f;
            const float w = fmaf(na1, t0, t1);
            v0 = fmaf(Qme.x, w,  fmaf(Qme.y, t0, v0));
            v1 = fmaf(Qme.z, t0, fmaf(Qme.y, t1, v1));
        }

        // reconstruct stream-B incoming: uB = A^16*u + dA
        const float wr  = fmaf(na1, v0, v1);
        const float uB0 = fmaf(al16, wr, fmaf(be16, v0, s1.x));
        const float uB1 = fmaf(ga16, v0, fmaf(be16, v1, s2.x));

        // phase 2: packed homogeneous correction y(t) += [A^t * u]_0
        f32x2 w0 = {v0, uB0}, w1 = {v1, uB1};
        #pragma unroll
        for (int t = 0; t < kHalf; ++t) {
            const f32x2 c = w0;
            X[t] = pk_add(X[t], c);
            w0 = pk_fma(na1p, c, w1);
            w1 = pk_mul(na2p, c);
        }
    }

    // ---- unpack + store ----
    {
        float4* op = reinterpret_cast<float4*>(out + (size_t)ch * kFrame + lane * 32);
        #pragma unroll
        for (int k = 0; k < 4; ++k) {
            op[k]     = float4{X[4 * k + 0].x, X[4 * k + 1].x, X[4 * k + 2].x, X[4 * k + 3].x};
            op[k + 4] = float4{X[4 * k + 0].y, X[4 * k + 1].y, X[4 * k + 2].y, X[4 * k + 3].y};
        }
    }
}

} // namespace

extern "C" void kernel_launch(void* const* d_in, const int* in_sizes, int n_in,
                              void* d_out, int out_size, void* d_ws, size_t ws_size,
                              hipStream_t stream)
{
    (void)d_ws; (void)ws_size; (void)n_in; (void)in_sizes;
    const float* audio  = (const float*)d_in[0];
    const float* params = (const float*)d_in[1];
    float* outp = (float*)d_out;

    const int channels = out_size / kFrame;        // 2048
    hipLaunchKernelGGL(biquad_chain_kernel, dim3(channels), dim3(64), 0, stream,
                       audio, params, outp);
}